// Round 8
// baseline (1947.073 us; speedup 1.0000x reference)
//
#include <hip/hip_runtime.h>

// Problem constants (B=16, N=M=1024, D=32)
constexpr int   NN       = 1024;
constexpr float EPSf     = 1e-3f;
constexpr int   MAX_ITER = 100;

// exp2-domain scale: arg = (v - C) * (1/eps) * log2(e)
#define K2      1442.6950408889634f
#define TWOK2   2885.3900817779268f
#define LN2f    0.6931471805599453f
#define INV_LN2 1.4426950408889634f
#define INV_EPS 1000.0f
#define LOGK    (-6.9314616f)   // log(1/1024 + 1e-8)

#define EXP2F(x) __builtin_amdgcn_exp2f(x)   // 2^x
#define LOG2F(x) __builtin_amdgcn_logf(x)    // log2(x)

typedef _Float16 f16x8 __attribute__((ext_vector_type(8)));
typedef float    f32x4 __attribute__((ext_vector_type(4)));

// (m,s) streaming-LSE merge: (ma,sa) <- (ma,sa) (+) (mb,sb)
__device__ __forceinline__ void msmerge(float& ma, float& sa, float mb, float sb)
{
    const float m2 = fmaxf(ma, mb);
    sa = fmaf(sa, EXP2F(ma - m2), sb * EXP2F(mb - m2));
    ma = m2;
}

// ---------------------------------------------------------------------------
// prep: X,Y fp32 -> fp16 copies + fp32 row sum-of-squares. C never
// materialized: all consumers use C = xsq_i + ysq_j - 2<x,y> (same fp16+MFMA
// path everywhere -> consistent C).
// ---------------------------------------------------------------------------
__global__ __launch_bounds__(256) void prep(
    const float* __restrict__ X, const float* __restrict__ Y,
    _Float16* __restrict__ Xh, _Float16* __restrict__ Yh,
    float* __restrict__ xsq, float* __restrict__ ysq)
{
    const int gid = blockIdx.x * 256 + threadIdx.x;   // 0..32767
    const float* src; _Float16* dst; float* sq; int row;
    if (gid < 16384) { src = X; dst = Xh; sq = xsq; row = gid; }
    else             { src = Y; dst = Yh; sq = ysq; row = gid - 16384; }

    const float4* s4 = (const float4*)(src + (size_t)row * 32);
    float acc = 0.f;
#pragma unroll
    for (int i = 0; i < 4; ++i) {
        float4 a = s4[2 * i], b = s4[2 * i + 1];
        acc += a.x*a.x + a.y*a.y + a.z*a.z + a.w*a.w;
        acc += b.x*b.x + b.y*b.y + b.z*b.z + b.w*b.w;
        f16x8 h = {(_Float16)a.x, (_Float16)a.y, (_Float16)a.z, (_Float16)a.w,
                   (_Float16)b.x, (_Float16)b.y, (_Float16)b.z, (_Float16)b.w};
        *(f16x8*)(dst + (size_t)row * 32 + i * 8) = h;
    }
    sq[row] = acc;
}

// XOR-swizzled LDS slot (r7-proven): conflict-free b128 reads/writes.
#define YSLOT(c, k) (((c) << 5) + (((k) ^ (((c) >> 1) & 3)) << 3))   // f16 units

// ---------------------------------------------------------------------------
// ONE kernel per Sinkhorn iteration (halves dispatch count vs r7):
//  P0: v_it[j] = exact LSE-combine of 16 per-block (m,s) col-partials emitted
//      by iteration it-1 (v_0 = 0). Redundant per block, trivial cost.
//  P1: u-update (row LSE) — r7's proven fast path (shift by prev-u) with
//      block-uniform max-shifted fallback. err accumulated per batch.
//  P2: col-partials for v_{it+1}: second MFMA loop, ONLINE max-shifted (m,s)
//      per column over this block's 64 rows -> Sp[(b,blk)][j] (exact, no
//      fallback ever needed for v).
// Freeze chain (reference semantics, triggering update applied): frozen(it) =
// it>0 && sum_b err[it-1][b] < 1.6 — read by every block, stream-ordered.
// Grid 256 x 1024: block (b=blk&15) owns 64 rows x 1024 cols of batch b.
// ---------------------------------------------------------------------------
__global__ __launch_bounds__(1024, 1) void sink_iter(
    const _Float16* __restrict__ Xh, const _Float16* __restrict__ Yh,
    const float* __restrict__ xsq, const float* __restrict__ ysq,
    float* __restrict__ u,          // [16][1024]
    float2* __restrict__ Sp,        // [16*16][1024] (m,s) col-partials
    float* __restrict__ err,        // [100][16]
    int it)
{
    __shared__ _Float16 Yl[32768];     // 64 KB B-tile, swizzled
    __shared__ float  wk[1024];        // (v_it - ysq) * K2
    __shared__ float  bks[1024];       // ysq * K2
    __shared__ float  mrg[64][8];
    __shared__ float2 colp[4][1024];   // 32 KB wr-partials
    __shared__ float  unew[64];
    __shared__ int    s_fb, s_frz;

    const int tid = threadIdx.x;
    const int b   = blockIdx.x & 15, blk = blockIdx.x >> 4;

    if (it > 0) {       // freeze check (every block, locally; err complete)
        if (tid == 0) {
            float e = 0.f;
            const float* ep = err + (it - 1) * 16;
#pragma unroll
            for (int q = 0; q < 16; ++q) e += ep[q];
            s_frz = (e < 1.6f) ? 1 : 0;
        }
        __syncthreads();
        if (s_frz) return;   // frozen: u and Sp keep converged values
    }
    if (tid == 0) s_fb = 0;

    {   // stage Yh[b] swizzled + P0 combine v + wk/bks
        const float4* src = (const float4*)(Yh + ((size_t)b << 15));
#pragma unroll
        for (int i = 0; i < 4; ++i) {
            const int g = tid + (i << 10);
            const int row = g >> 2, k = g & 3;
            *(float4*)(Yl + YSLOT(row, k)) = src[g];
        }
        float vj = 0.f;
        if (it > 0) {
            const float2* sp = Sp + ((size_t)b << 14) + tid;   // [k][tid]
            float2 p0 = sp[0];
            float M = p0.x, S = p0.y;
#pragma unroll
            for (int k = 1; k < 16; ++k) {
                float2 p = sp[k << 10];
                msmerge(M, S, p.x, p.y);
            }
            vj = EPSf * (LOGK - (M + LOG2F(S)) * LN2f);
        }
        const float bq = ysq[(b << 10) + tid];
        wk[tid]  = (vj - bq) * K2;
        bks[tid] = bq * K2;
    }
    __syncthreads();

    const int wave = tid >> 6, lane = tid & 63;
    const int wr = wave >> 2, wc = wave & 3;
    const int l15 = lane & 15, l4 = lane >> 4;
    const int rowb = (blk << 6) + (wr << 4);            // wave's 16-row stripe

    // A fragment: rows rowb+l15, k = l4*8..+7
    const f16x8 afrag = *(const f16x8*)(Xh + ((size_t)b << 15) +
                                        ((size_t)(rowb + l15) << 5) + (l4 << 3));
    // per-D-row terms: rows rowb + l4*4 + r
    const float4 xs4 = *(const float4*)(xsq + (b << 10) + rowb + (l4 << 2));
    const float4 uo4 = *(const float4*)(u + (b << 10) + rowb + (l4 << 2));
    const float xk[4] = {xs4.x * K2, xs4.y * K2, xs4.z * K2, xs4.w * K2};
    float xm[4];
    {   const float u4[4] = {uo4.x, uo4.y, uo4.z, uo4.w};
#pragma unroll
        for (int r = 0; r < 4; ++r)
            xm[r] = xk[r] + (LOGK - u4[r] * INV_EPS) * INV_LN2;
    }
    float wreg[16];
#pragma unroll
    for (int t = 0; t < 16; ++t) wreg[t] = wk[(wc << 8) + (t << 4) + l15];

    // -------- P1 FAST PATH: plain sums shifted by prev-u M0 --------
    float s[4] = {0.f, 0.f, 0.f, 0.f};
#pragma unroll 4
    for (int t = 0; t < 16; ++t) {
        const int col = (wc << 8) + (t << 4) + l15;
        const f16x8 bfrag = *(const f16x8*)(Yl + YSLOT(col, l4));
        f32x4 z = {0.f, 0.f, 0.f, 0.f};
        f32x4 d = __builtin_amdgcn_mfma_f32_16x16x32_f16(afrag, bfrag, z, 0, 0, 0);
#pragma unroll
        for (int r = 0; r < 4; ++r)
            s[r] += EXP2F(fmaf(d[r], TWOK2, wreg[t] - xm[r]));
    }
#pragma unroll
    for (int off = 1; off < 16; off <<= 1)
#pragma unroll
        for (int r = 0; r < 4; ++r) s[r] += __shfl_xor(s[r], off);
    if (l15 == 0) {
#pragma unroll
        for (int r = 0; r < 4; ++r) mrg[(wr << 4) + (l4 << 2) + r][wc] = s[r];
    }
    __syncthreads();

    float S = 0.f, uo = 0.f, M0r = 0.f;
    int gr = 0;
    if (tid < 64) {
        S = mrg[tid][0] + mrg[tid][1] + mrg[tid][2] + mrg[tid][3];
        gr = (b << 10) + (blk << 6) + tid;
        uo = u[gr];
        M0r = (LOGK - uo * INV_EPS) * INV_LN2;
        if (!(S >= 1e-27f && S <= 1e38f)) s_fb = 1;
    }
    __syncthreads();

    if (!s_fb) {
        if (tid < 64) {
            const float nv = EPSf * (LOGK - (M0r + LOG2F(S)) * LN2f);
            unew[tid] = nv;
            u[gr] = nv;
            float werr = fabsf(nv - uo);
#pragma unroll
            for (int off = 32; off > 0; off >>= 1) werr += __shfl_xor(werr, off);
            if (tid == 0) atomicAdd(err + it * 16 + b, werr);
        }
    } else {
        // -------- P1 FALLBACK: online max-shifted (it=0, drift) --------
        float m[4] = {-3.4e38f, -3.4e38f, -3.4e38f, -3.4e38f};
        float sf[4] = {0.f, 0.f, 0.f, 0.f};
#pragma unroll 4
        for (int t = 0; t < 16; ++t) {
            const int col = (wc << 8) + (t << 4) + l15;
            const f16x8 bfrag = *(const f16x8*)(Yl + YSLOT(col, l4));
            f32x4 z = {0.f, 0.f, 0.f, 0.f};
            f32x4 d = __builtin_amdgcn_mfma_f32_16x16x32_f16(afrag, bfrag, z, 0, 0, 0);
#pragma unroll
            for (int r = 0; r < 4; ++r) {
                const float arg = fmaf(d[r], TWOK2, wreg[t] - xk[r]);
                const float big = fmaxf(m[r], arg);
                const float e   = EXP2F(fminf(m[r], arg) - big);
                sf[r] = (arg > m[r]) ? fmaf(sf[r], e, 1.0f) : (sf[r] + e);
                m[r] = big;
            }
        }
#pragma unroll
        for (int off = 1; off < 16; off <<= 1)
#pragma unroll
            for (int r = 0; r < 4; ++r)
                msmerge(m[r], sf[r], __shfl_xor(m[r], off), __shfl_xor(sf[r], off));
        if (l15 == 0) {
#pragma unroll
            for (int r = 0; r < 4; ++r) {
                const int rb = (wr << 4) + (l4 << 2) + r;
                mrg[rb][wc]     = m[r];
                mrg[rb][4 + wc] = sf[r];
            }
        }
        __syncthreads();
        if (tid < 64) {
            float M = mrg[tid][0], Sf = mrg[tid][4];
            msmerge(M, Sf, mrg[tid][1], mrg[tid][5]);
            msmerge(M, Sf, mrg[tid][2], mrg[tid][6]);
            msmerge(M, Sf, mrg[tid][3], mrg[tid][7]);
            const float nv = EPSf * (LOGK - (M + LOG2F(Sf)) * LN2f);
            unew[tid] = nv;
            u[gr] = nv;
            float werr = fabsf(nv - uo);
#pragma unroll
            for (int off = 32; off > 0; off >>= 1) werr += __shfl_xor(werr, off);
            if (tid == 0) atomicAdd(err + it * 16 + b, werr);
        }
    }
    __syncthreads();   // unew visible to all waves

    // -------- P2: col-partials for v_{it+1} (exact online max-shift) --------
    float am[4];
#pragma unroll
    for (int r = 0; r < 4; ++r)
        am[r] = unew[(wr << 4) + (l4 << 2) + r] * K2 - xk[r];
    float bkreg[16];
#pragma unroll
    for (int t = 0; t < 16; ++t) bkreg[t] = bks[(wc << 8) + (t << 4) + l15];

    float cm[16], cs[16];
#pragma unroll
    for (int t = 0; t < 16; ++t) { cm[t] = -3.4e38f; cs[t] = 0.f; }

#pragma unroll 4
    for (int t = 0; t < 16; ++t) {
        const int col = (wc << 8) + (t << 4) + l15;
        const f16x8 bfrag = *(const f16x8*)(Yl + YSLOT(col, l4));
        f32x4 z = {0.f, 0.f, 0.f, 0.f};
        f32x4 d = __builtin_amdgcn_mfma_f32_16x16x32_f16(afrag, bfrag, z, 0, 0, 0);
#pragma unroll
        for (int r = 0; r < 4; ++r) {
            // arg2 = (u_new_i - C_ij) * K2 (exp2 domain)
            const float arg = fmaf(d[r], TWOK2, am[r] - bkreg[t]);
            const float big = fmaxf(cm[t], arg);
            const float e   = EXP2F(fminf(cm[t], arg) - big);
            cs[t] = (arg > cm[t]) ? fmaf(cs[t], e, 1.0f) : (cs[t] + e);
            cm[t] = big;
        }
    }
    // merge across the 4 l4 row-groups (partners at lane^16, lane^32)
#pragma unroll
    for (int off = 16; off <= 32; off <<= 1)
#pragma unroll
        for (int t = 0; t < 16; ++t) {
            const float mo = __shfl_xor(cm[t], off);
            const float so = __shfl_xor(cs[t], off);
            msmerge(cm[t], cs[t], mo, so);
        }
    if (l4 == 0) {
#pragma unroll
        for (int t = 0; t < 16; ++t)
            colp[wr][(wc << 8) + (t << 4) + l15] = make_float2(cm[t], cs[t]);
    }
    __syncthreads();

    {   // wr-merge + coalesced store of this block's column partial
        float2 q0 = colp[0][tid];
        float M = q0.x, Sv = q0.y;
        float2 q1 = colp[1][tid]; msmerge(M, Sv, q1.x, q1.y);
        float2 q2 = colp[2][tid]; msmerge(M, Sv, q2.x, q2.y);
        float2 q3 = colp[3][tid]; msmerge(M, Sv, q3.x, q3.y);
        Sp[(((size_t)b << 4) + blk << 10) + tid] = make_float2(M, Sv);
    }
}

// ---------------------------------------------------------------------------
// cost = mean_b sum_ij exp((u_i + v_j - C_ij)/eps) * C_ij; v_final combined
// from Sp exactly as sink_iter's P0; C via the SAME fp16+MFMA path.
// ---------------------------------------------------------------------------
__global__ __launch_bounds__(1024, 1) void cost_mfma(
    const _Float16* __restrict__ Xh, const _Float16* __restrict__ Yh,
    const float* __restrict__ xsq, const float* __restrict__ ysq,
    const float* __restrict__ u, const float2* __restrict__ Sp,
    float* __restrict__ out)
{
    __shared__ _Float16 Yl[32768];
    __shared__ float vkl[1024];   // v_final * K2
    __shared__ float red[16];
    const int tid = threadIdx.x;
    const int b   = blockIdx.x & 15, blk = blockIdx.x >> 4;

    {   const float4* src = (const float4*)(Yh + ((size_t)b << 15));
#pragma unroll
        for (int i = 0; i < 4; ++i) {
            const int g = tid + (i << 10);
            const int row = g >> 2, k = g & 3;
            *(float4*)(Yl + YSLOT(row, k)) = src[g];
        }
        const float2* sp = Sp + ((size_t)b << 14) + tid;
        float2 p0 = sp[0];
        float M = p0.x, S = p0.y;
#pragma unroll
        for (int k = 1; k < 16; ++k) {
            float2 p = sp[k << 10];
            msmerge(M, S, p.x, p.y);
        }
        vkl[tid] = EPSf * (LOGK - (M + LOG2F(S)) * LN2f) * K2;
    }
    __syncthreads();

    const int wave = tid >> 6, lane = tid & 63;
    const int wr = wave >> 2, wc = wave & 3;
    const int l15 = lane & 15, l4 = lane >> 4;
    const int rowb = (blk << 6) + (wr << 4);

    const f16x8 afrag = *(const f16x8*)(Xh + ((size_t)b << 15) +
                                        ((size_t)(rowb + l15) << 5) + (l4 << 3));
    const float4 xs4 = *(const float4*)(xsq + (b << 10) + rowb + (l4 << 2));
    const float xs[4] = {xs4.x, xs4.y, xs4.z, xs4.w};
    const float4 uu4 = *(const float4*)(u + (b << 10) + rowb + (l4 << 2));
    const float uk[4] = {uu4.x * K2, uu4.y * K2, uu4.z * K2, uu4.w * K2};

    float vk[16], ys[16];
#pragma unroll
    for (int t = 0; t < 16; ++t) {
        const int cl = (wc << 8) + (t << 4) + l15;
        vk[t] = vkl[cl];
        ys[t] = ysq[(b << 10) + cl];
    }

    float csum = 0.f;
#pragma unroll 4
    for (int t = 0; t < 16; ++t) {
        const int col = (wc << 8) + (t << 4) + l15;
        const f16x8 bfrag = *(const f16x8*)(Yl + YSLOT(col, l4));
        f32x4 z = {0.f, 0.f, 0.f, 0.f};
        f32x4 d = __builtin_amdgcn_mfma_f32_16x16x32_f16(afrag, bfrag, z, 0, 0, 0);
#pragma unroll
        for (int r = 0; r < 4; ++r) {
            const float C   = fmaf(-2.f, d[r], xs[r] + ys[t]);
            const float arg = fmaf(C, -K2, uk[r] + vk[t]);
            csum += EXP2F(arg) * C;
        }
    }
#pragma unroll
    for (int off = 32; off > 0; off >>= 1) csum += __shfl_xor(csum, off);

    if (lane == 0) red[wave] = csum;
    __syncthreads();
    if (tid == 0) {
        float tot = 0.f;
#pragma unroll
        for (int w = 0; w < 16; ++w) tot += red[w];
        atomicAdd(out, tot * (1.0f / 16.0f));
    }
}

extern "C" void kernel_launch(void* const* d_in, const int* in_sizes, int n_in,
                              void* d_out, int out_size, void* d_ws, size_t ws_size,
                              hipStream_t stream) {
    const float* x = (const float*)d_in[0];  // output: [16,1024,32] fp32
    const float* y = (const float*)d_in[1];  // labels: [16,1024,32] fp32

    char* wsb = (char*)d_ws;
    _Float16* Xh = (_Float16*)wsb;                     // 1 MB  [16][1024][32]
    _Float16* Yh = (_Float16*)(wsb + (1u << 20));      // 1 MB
    float2* Sp   = (float2*)(wsb + (2u << 20));        // 2 MB  [256][1024]
    float* xsq   = (float*)(wsb + (4u << 20));         // 16384 f
    float* ysq   = xsq + 16384;                        // 16384 f
    float* u     = ysq + 16384;                        // 16384 f
    float* err   = u + 16384;                          // [100][16]
    float* out   = (float*)d_out;

    // u and err contiguous — zero them (+ out) every call
    (void)hipMemsetAsync(u, 0, (size_t)(16384 + 1600) * 4, stream);
    (void)hipMemsetAsync(out, 0, sizeof(float), stream);

    prep<<<dim3(128), dim3(256), 0, stream>>>(x, y, Xh, Yh, xsq, ysq);

    // one dispatch per iteration (u-update + v-partials fused)
    for (int it = 0; it < MAX_ITER; ++it)
        sink_iter<<<dim3(256), dim3(1024), 0, stream>>>(
            Xh, Yh, xsq, ysq, u, Sp, err, it);

    cost_mfma<<<dim3(256), dim3(1024), 0, stream>>>(Xh, Yh, xsq, ysq, u, Sp, out);
}